// Round 4
// baseline (300.461 us; speedup 1.0000x reference)
//
#include <hip/hip_runtime.h>
#include <hip/hip_bf16.h>
#include <cstdint>
#include <cstddef>

#define DIMM 2048
#define NHEADS 32
#define HDIM 64
#define SEQ 2048
#define NBATCH 2
#define ROWS 4096
#define NFREQ 16
#define NKT 64  // K=2048 / BK=32

typedef __bf16 bfv8 __attribute__((ext_vector_type(8)));
typedef float f32x4v __attribute__((ext_vector_type(4)));
typedef float f32x16 __attribute__((ext_vector_type(16)));

__device__ __forceinline__ void gload16(const void* g, void* l) {
  __builtin_amdgcn_global_load_lds((const __attribute__((address_space(1))) void*)g,
                                   (__attribute__((address_space(3))) void*)l, 16, 0, 0);
}

__device__ __forceinline__ f32x4v mfma16(bfv8 a, bfv8 b, f32x4v c) {
  return __builtin_amdgcn_mfma_f32_16x16x32_bf16(a, b, c, 0, 0, 0);
}

__device__ __forceinline__ f32x16 mfma32(bfv8 a, bfv8 b, f32x16 c) {
  return __builtin_amdgcn_mfma_f32_32x32x16_bf16(a, b, c, 0, 0, 0);
}

__device__ __forceinline__ unsigned short f2bfu(float f) {
  __hip_bfloat16 h = __float2bfloat16(f);
  return __builtin_bit_cast(unsigned short, h);
}

__device__ __forceinline__ unsigned pack2bf(float a, float b) {
  return (unsigned)f2bfu(a) | ((unsigned)f2bfu(b) << 16);
}

// permlane32_swap semantics via shfl:
// new_a[l] = l<32 ? a[l] : b[l^32];  new_b[l] = l<32 ? a[l^32] : b[l]
__device__ __forceinline__ void swap32(unsigned& a, unsigned& b, const int hi) {
  const unsigned ta = (unsigned)__shfl_xor((int)a, 32);
  const unsigned tb = (unsigned)__shfl_xor((int)b, 32);
  const unsigned na = hi ? tb : a;
  const unsigned nb = hi ? b : ta;
  a = na;
  b = nb;
}

__device__ __forceinline__ void xcd_swizzle(int& bx, int& by) {
  const int gx = gridDim.x, nwg = gx * gridDim.y;
  const int orig = blockIdx.y * gx + blockIdx.x;
  const int q = nwg >> 3, r = nwg & 7;
  const int xcd = orig & 7, loc = orig >> 3;
  const int wg = (xcd < r ? xcd * (q + 1) : r * (q + 1) + (xcd - r) * q) + loc;
  bx = wg % gx;
  by = wg / gx;
}

// ---------------- RoPE cos/sin table: [SEQ][16] f32 each ----------------
__global__ __launch_bounds__(256) void rope_tab_kernel(float* __restrict__ ct,
                                                       float* __restrict__ st) {
  const int i = blockIdx.x * 256 + threadIdx.x;
  if (i >= SEQ * NFREQ) return;
  const int pos = i >> 4, f = i & 15;
  const float freq = powf(10000.0f, -(float)f / 16.0f);
  const float ang = (float)pos * freq;
  ct[i] = cosf(ang);
  st[i] = sinf(ang);
}

// ---------------- transpose + cast f32[K][N] -> bf16[N][K] ----------------
__global__ __launch_bounds__(256) void transpose_cast_kernel(const float* __restrict__ W,
                                                             __hip_bfloat16* __restrict__ WT,
                                                             int K, int N) {
  __shared__ float tile[32][33];
  const int n0 = blockIdx.x * 32, k0 = blockIdx.y * 32;
  const int tx = threadIdx.x, ty = threadIdx.y;
#pragma unroll
  for (int j = 0; j < 4; ++j)
    tile[ty + j * 8][tx] = W[(size_t)(k0 + ty + j * 8) * N + n0 + tx];
  __syncthreads();
#pragma unroll
  for (int j = 0; j < 4; ++j)
    WT[(size_t)(n0 + ty + j * 8) * K + k0 + tx] = __float2bfloat16(tile[tx][ty + j * 8]);
}

// ---------------- LayerNorm f32 -> bf16, one row per block ----------------
__global__ __launch_bounds__(256) void ln_kernel(const float* __restrict__ x,
                                                 const float* __restrict__ lw,
                                                 const float* __restrict__ lb,
                                                 __hip_bfloat16* __restrict__ h) {
  const int row = blockIdx.x;
  const int t = threadIdx.x;
  const float4* xr = (const float4*)(x + (size_t)row * DIMM);
  float4 a = xr[t * 2], b = xr[t * 2 + 1];
  float e[8];
  *(float4*)e = a; *(float4*)(e + 4) = b;
  float s = 0.f, ss = 0.f;
#pragma unroll
  for (int j = 0; j < 8; ++j) { s += e[j]; ss += e[j] * e[j]; }
#pragma unroll
  for (int o = 1; o < 64; o <<= 1) { s += __shfl_xor(s, o); ss += __shfl_xor(ss, o); }
  __shared__ float red[8];
  const int wid = t >> 6;
  if ((t & 63) == 0) { red[wid * 2] = s; red[wid * 2 + 1] = ss; }
  __syncthreads();
  s = red[0] + red[2] + red[4] + red[6];
  ss = red[1] + red[3] + red[5] + red[7];
  const float mu = s * (1.f / DIMM);
  const float var = ss * (1.f / DIMM) - mu * mu;
  const float rs = rsqrtf(var + 1e-5f);
  const float4* w4 = (const float4*)lw;
  const float4* b4 = (const float4*)lb;
  float4 wa = w4[t * 2], wb = w4[t * 2 + 1], ba = b4[t * 2], bb = b4[t * 2 + 1];
  float wv[8], bv[8];
  *(float4*)wv = wa; *(float4*)(wv + 4) = wb;
  *(float4*)bv = ba; *(float4*)(bv + 4) = bb;
  unsigned short hv[8];
#pragma unroll
  for (int j = 0; j < 8; ++j)
    hv[j] = f2bfu((e[j] - mu) * rs * wv[j] + bv[j]);
  *(uint4*)((char*)h + (size_t)row * (DIMM * 2) + t * 16) = *(uint4*)hv;
}

// ---------------- 256x128xK pipelined GEMM core (BK=32, 2 LDS bufs, counted vmcnt) ----
// LDS buf (24 KB): A [256 rows][64 B] at +0, B [128 rows][64 B] at +16384.
// Swizzle: byte ^= ((row>>1)&3)<<4 (both sides). 6 gloads/thread per K-tile.
// Schedule/iter: ds_read 12 frags; lgkmcnt(0); barrier; STAGE(kt+2 -> this buf);
//                32 MFMA (setprio); vmcnt(6) [kt+1 landed, kt+2 in flight]; barrier.
__device__ __forceinline__ void stage_tile(const char* Ab, const char* Bb,
                                           int brow, int bcol, int kt, char* buf,
                                           int tid) {
  const int wid = tid >> 6, lane = tid & 63;
#pragma unroll
  for (int i = 0; i < 4; ++i) {
    const int fw = wid * 1024 + i * 4096;
    const int f = fw + lane * 16;
    const int lr = f >> 6;
    const int src = (f & 63) ^ (((lr >> 1) & 3) << 4);
    gload16(Ab + (size_t)(brow + lr) * 4096 + kt * 64 + src, buf + fw);
  }
#pragma unroll
  for (int i = 0; i < 2; ++i) {
    const int fw = wid * 1024 + i * 4096;
    const int f = fw + lane * 16;
    const int lr = f >> 6;
    const int src = (f & 63) ^ (((lr >> 1) & 3) << 4);
    gload16(Bb + (size_t)(bcol + lr) * 4096 + kt * 64 + src, buf + 16384 + fw);
  }
}

__device__ __forceinline__ void gemm_core(const char* Ab, const char* Bb,
                                          int brow, int bcol, char* lds,
                                          f32x4v acc[8][4]) {
  const int tid = threadIdx.x;
  const int lane = tid & 63, wid = tid >> 6;
  const int g = lane >> 4, ln15 = lane & 15;
  const int wr = wid >> 1, wc = wid & 1;
  stage_tile(Ab, Bb, brow, bcol, 0, lds, tid);
  stage_tile(Ab, Bb, brow, bcol, 1, lds + 24576, tid);
  asm volatile("s_waitcnt vmcnt(6)" ::: "memory");  // tile 0 landed, tile 1 in flight
  __syncthreads();
  for (int kt = 0; kt < NKT; ++kt) {
    char* buf = lds + (kt & 1) * 24576;
    bfv8 af[8], bfr[4];
#pragma unroll
    for (int mf = 0; mf < 8; ++mf) {
      const int ra = wr * 128 + mf * 16 + ln15;
      af[mf] = *(const bfv8*)(buf + ra * 64 + ((g * 16) ^ (((ra >> 1) & 3) << 4)));
    }
#pragma unroll
    for (int nf = 0; nf < 4; ++nf) {
      const int rb = wc * 64 + nf * 16 + ln15;
      bfr[nf] = *(const bfv8*)(buf + 16384 + rb * 64 + ((g * 16) ^ (((rb >> 1) & 3) << 4)));
    }
    asm volatile("s_waitcnt lgkmcnt(0)" ::: "memory");
    __builtin_amdgcn_sched_barrier(0);
    __syncthreads();  // every wave done READING buf -> safe to overwrite
    if (kt + 2 < NKT) stage_tile(Ab, Bb, brow, bcol, kt + 2, buf, tid);
    __builtin_amdgcn_s_setprio(1);
#pragma unroll
    for (int mf = 0; mf < 8; ++mf)
#pragma unroll
      for (int nf = 0; nf < 4; ++nf)
        acc[mf][nf] = mfma16(af[mf], bfr[nf], acc[mf][nf]);
    __builtin_amdgcn_s_setprio(0);
    if (kt + 2 < NKT) {
      asm volatile("s_waitcnt vmcnt(6)" ::: "memory");  // kt+1 landed; kt+2 stays in flight
    } else {
      asm volatile("s_waitcnt vmcnt(0)" ::: "memory");  // tail drain
    }
    __syncthreads();
  }
}

// ---------------- QKV GEMM + bias + RoPE; q,k -> [n*h][s][64]; v -> VT [n*h][64][s] ----
__global__ __launch_bounds__(256, 2) void gemm_qkv_kernel(
    const __hip_bfloat16* __restrict__ A, const __hip_bfloat16* __restrict__ BT,
    const float* __restrict__ bqkv, const float* __restrict__ ct, const float* __restrict__ st,
    __hip_bfloat16* __restrict__ qb, __hip_bfloat16* __restrict__ kb,
    __hip_bfloat16* __restrict__ vb) {
  __shared__ char lds[49152];
  const f32x4v fz = {0.f, 0.f, 0.f, 0.f};
  f32x4v acc[8][4];
#pragma unroll
  for (int mf = 0; mf < 8; ++mf)
#pragma unroll
    for (int nf = 0; nf < 4; ++nf) acc[mf][nf] = fz;
  int bx, by;
  xcd_swizzle(bx, by);
  const int brow = by * 256, bcol = bx * 128;
  gemm_core((const char*)A, (const char*)BT, brow, bcol, lds, acc);

  const int tid = threadIdx.x, lane = tid & 63, wid = tid >> 6;
  const int g = lane >> 4, ln15 = lane & 15;
  const int wr = wid >> 1, wc = wid & 1;
  const int cb = bcol + wc * 64;
  const int which = cb >> 11;
  const int head = (cb & 2047) >> 6;
  float bias[4];
#pragma unroll
  for (int nf = 0; nf < 4; ++nf) bias[nf] = bqkv[cb + nf * 16 + ln15];

  if (which == 2) {
    // V: transpose wave's 128pos x 64d subtile in two 64-row passes via private 8KB LDS
    char* tp = lds + wid * 8192;
    const int nidx = brow >> 11;
    const size_t vhead = ((size_t)nidx * NHEADS + head) * (HDIM * SEQ);
#pragma unroll
    for (int hm = 0; hm < 2; ++hm) {
      if (hm == 1) {
        asm volatile("s_waitcnt lgkmcnt(0)" ::: "memory");  // pass-0 tp reads done (WAR)
        __builtin_amdgcn_sched_barrier(0);
      }
#pragma unroll
      for (int mf4 = 0; mf4 < 4; ++mf4)
#pragma unroll
        for (int r = 0; r < 4; ++r) {
          const int mf = hm * 4 + mf4;
          const int posl = mf4 * 16 + g * 4 + r;
#pragma unroll
          for (int nf = 0; nf < 4; ++nf) {
            const int d = nf * 16 + ln15;
            *(unsigned short*)(tp + d * 128 + ((posl * 2) ^ ((d & 7) << 4))) =
                f2bfu(acc[mf][nf][r] + bias[nf]);
          }
        }
      asm volatile("s_waitcnt lgkmcnt(0)" ::: "memory");
      __builtin_amdgcn_sched_barrier(0);
      const int posb = (brow & 2047) + wr * 128 + hm * 64;
#pragma unroll
      for (int i = 0; i < 8; ++i) {
        const int dl = i * 8 + (lane >> 3);
        const int cs = (lane & 7) ^ (dl & 7);
        const uint4 val = *(const uint4*)(tp + dl * 128 + cs * 16);
        *(uint4*)((char*)vb + (vhead + (size_t)dl * SEQ + posb + (lane & 7) * 8) * 2) = val;
      }
    }
  } else {
    __hip_bfloat16* dst = (which == 0) ? qb : kb;
#pragma unroll
    for (int mf = 0; mf < 8; ++mf)
#pragma unroll
      for (int r = 0; r < 4; ++r) {
        const int row = brow + wr * 128 + mf * 16 + g * 4 + r;
        const int nidx = row >> 11, pos = row & 2047;
        float v0 = acc[mf][0][r] + bias[0];
        float v1 = acc[mf][1][r] + bias[1];
        float v2 = acc[mf][2][r] + bias[2];
        float v3 = acc[mf][3][r] + bias[3];
        const float c0 = ct[pos * 16 + ln15], s0 = st[pos * 16 + ln15];
        const float x1 = v0, x2 = v1;
        v0 = x1 * c0 - x2 * s0;
        v1 = x2 * c0 + x1 * s0;
        __hip_bfloat16* p = dst + (((size_t)(nidx * NHEADS + head)) * SEQ + pos) * HDIM;
        p[ln15] = __float2bfloat16(v0);
        p[16 + ln15] = __float2bfloat16(v1);
        p[32 + ln15] = __float2bfloat16(v2);
        p[48 + ln15] = __float2bfloat16(v3);
      }
  }
}

// ---------------- out-proj GEMM + bias + residual -> f32 out ----------------
__global__ __launch_bounds__(256, 2) void gemm_out_kernel(
    const __hip_bfloat16* __restrict__ A, const __hip_bfloat16* __restrict__ BT,
    const float* __restrict__ bout, const float* __restrict__ skip,
    float* __restrict__ out) {
  __shared__ char lds[49152];
  const f32x4v fz = {0.f, 0.f, 0.f, 0.f};
  f32x4v acc[8][4];
#pragma unroll
  for (int mf = 0; mf < 8; ++mf)
#pragma unroll
    for (int nf = 0; nf < 4; ++nf) acc[mf][nf] = fz;
  int bx, by;
  xcd_swizzle(bx, by);
  const int brow = by * 256, bcol = bx * 128;
  gemm_core((const char*)A, (const char*)BT, brow, bcol, lds, acc);

  const int tid = threadIdx.x, lane = tid & 63, wid = tid >> 6;
  const int g = lane >> 4, ln15 = lane & 15;
  const int wr = wid >> 1, wc = wid & 1;
#pragma unroll
  for (int mf = 0; mf < 8; ++mf)
#pragma unroll
    for (int r = 0; r < 4; ++r) {
      const int row = brow + wr * 128 + mf * 16 + g * 4 + r;
      const float* xr = skip + (size_t)row * DIMM;
      float* orow = out + (size_t)row * DIMM;
#pragma unroll
      for (int nf = 0; nf < 4; ++nf) {
        const int c = bcol + wc * 64 + nf * 16 + ln15;
        orow[c] = acc[mf][nf][r] + bout[c] + xr[c];
      }
    }
}

// ---------------- causal flash attention, swapped-QK^T 32x32 structure ----------------
__global__ __launch_bounds__(256) void attn_kernel(
    const __hip_bfloat16* __restrict__ qb, const __hip_bfloat16* __restrict__ kb,
    const __hip_bfloat16* __restrict__ vtb, __hip_bfloat16* __restrict__ ob) {
  __shared__ char sm[33280];  // K dbuf 2x8K | VT dbuf 2x8K | lred 512B
  float* lred = (float*)(sm + 32768);
  const int tid = threadIdx.x, lane = tid & 63, wid = tid >> 6;
  const int ln31 = lane & 31, hi = lane >> 5;
  const int head = blockIdx.x;
  const int qbi = (int)gridDim.y - 1 - (int)blockIdx.y;  // heavy blocks dispatch first
  const size_t hb = (size_t)head * (SEQ * HDIM);
  const int q0 = qbi * 128;
  const int qw = q0 + wid * 32;
  const int qg = qw + ln31;
  const int nt = qbi * 2 + 2;
  const char* Kg = (const char*)(kb + hb);
  const char* Vg = (const char*)(vtb + hb);

  bfv8 qf[4];
  {
    const char* Qp = (const char*)(qb + hb) + (size_t)(qw + ln31) * 128 + hi * 16;
#pragma unroll
    for (int j = 0; j < 4; ++j) qf[j] = *(const bfv8*)(Qp + j * 32);
  }

  f32x16 o0, o1;
#pragma unroll
  for (int i = 0; i < 16; ++i) { o0[i] = 0.f; o1[i] = 0.f; }
  float m_run = -1e30f, l_run = 0.f;
  const float scale = 0.125f;
  const int swz = (ln31 & 7) << 4;

#pragma unroll
  for (int i = 0; i < 2; ++i) {
    const int f = (tid + i * 256) * 16;
    const int row = f >> 7;
    const int src = (f & 127) ^ ((row & 7) << 4);
    gload16(Kg + (size_t)row * 128 + src, sm + f);
    gload16(Vg + (size_t)row * 4096 + src, sm + 16384 + f);
  }
  asm volatile("s_waitcnt vmcnt(0)" ::: "memory");
  __syncthreads();

  for (int t = 0; t < nt; ++t) {
    const int kvb = t * 64;
    if (t + 1 < nt) {
      const int nb = (t + 1) & 1;
      const int kvb2 = kvb + 64;
#pragma unroll
      for (int i = 0; i < 2; ++i) {
        const int f = (tid + i * 256) * 16;
        const int row = f >> 7;
        const int src = (f & 127) ^ ((row & 7) << 4);
        gload16(Kg + (size_t)(kvb2 + row) * 128 + src, sm + nb * 8192 + f);
        gload16(Vg + (size_t)row * 4096 + (size_t)kvb2 * 2 + src, sm + 16384 + nb * 8192 + f);
      }
    }
    if (kvb <= qw + 31) {
      const char* ldsK = sm + (t & 1) * 8192;
      const char* ldsV = sm + 16384 + (t & 1) * 8192;
      f32x16 s0, s1;
#pragma unroll
      for (int i = 0; i < 16; ++i) { s0[i] = 0.f; s1[i] = 0.f; }
      __builtin_amdgcn_s_setprio(1);
#pragma unroll
      for (int j = 0; j < 4; ++j) {
        const int byt = j * 32 + hi * 16;
        const bfv8 k0 = *(const bfv8*)(ldsK + ln31 * 128 + (byt ^ swz));
        const bfv8 k1 = *(const bfv8*)(ldsK + (32 + ln31) * 128 + (byt ^ swz));
        s0 = mfma32(k0, qf[j], s0);
        s1 = mfma32(k1, qf[j], s1);
      }
      __builtin_amdgcn_s_setprio(0);
      float p[32];
#pragma unroll
      for (int r = 0; r < 16; ++r) { p[r] = s0[r] * scale; p[16 + r] = s1[r] * scale; }
      if (kvb + 63 > qw) {  // diagonal tile for this wave (compare vs MIN q-row)
#pragma unroll
        for (int r = 0; r < 16; ++r) {
          const int kvo = (r & 3) + 8 * (r >> 2) + 4 * hi;
          if (kvb + kvo > qg) p[r] = -1e30f;
          if (kvb + 32 + kvo > qg) p[16 + r] = -1e30f;
        }
      }
      float mx = p[0];
#pragma unroll
      for (int r = 1; r < 32; ++r) mx = fmaxf(mx, p[r]);
      mx = fmaxf(mx, __shfl_xor(mx, 32));
      if (!__all(mx <= m_run + 8.0f)) {  // defer-max (T13, THR=8)
        const float mn = fmaxf(m_run, mx);
        const float al = __expf(m_run - mn);
        m_run = mn;
        l_run *= al;
        lred[wid * 32 + ln31] = al;
        asm volatile("s_waitcnt lgkmcnt(0)" ::: "memory");
        __builtin_amdgcn_sched_barrier(0);
#pragma unroll
        for (int r = 0; r < 16; ++r) {
          const float a = lred[wid * 32 + (r & 3) + 8 * (r >> 2) + 4 * hi];
          o0[r] *= a;
          o1[r] *= a;
        }
      }
      float ps = 0.f;
#pragma unroll
      for (int r = 0; r < 32; ++r) { p[r] = __expf(p[r] - m_run); ps += p[r]; }
      ps += __shfl_xor(ps, 32);
      l_run += ps;
      unsigned c[16];
#pragma unroll
      for (int i = 0; i < 16; ++i) c[i] = pack2bf(p[2 * i], p[2 * i + 1]);
      bfv8 paf[4];
#pragma unroll
      for (int fI = 0; fI < 4; ++fI) {
        unsigned a0 = c[fI * 4 + 0], b0 = c[fI * 4 + 2];
        unsigned a1 = c[fI * 4 + 1], b1 = c[fI * 4 + 3];
        swap32(a0, b0, hi);
        swap32(a1, b1, hi);
        union { unsigned u[4]; bfv8 v; } w;
        w.u[0] = a0; w.u[1] = a1; w.u[2] = b0; w.u[3] = b1;
        paf[fI] = w.v;
      }
      __builtin_amdgcn_s_setprio(1);
#pragma unroll
      for (int ss = 0; ss < 4; ++ss) {
        const int byt = ss * 32 + hi * 16;
        const bfv8 v0 = *(const bfv8*)(ldsV + ln31 * 128 + (byt ^ swz));
        const bfv8 v1 = *(const bfv8*)(ldsV + (32 + ln31) * 128 + (byt ^ swz));
        o0 = mfma32(paf[ss], v0, o0);
        o1 = mfma32(paf[ss], v1, o1);
      }
      __builtin_amdgcn_s_setprio(0);
    }
    asm volatile("s_waitcnt vmcnt(0)" ::: "memory");
    __syncthreads();
  }

  lred[wid * 32 + ln31] = l_run;
  asm volatile("s_waitcnt lgkmcnt(0)" ::: "memory");
  __builtin_amdgcn_sched_barrier(0);
  const int nidx = head >> 5, hh = head & 31;
#pragma unroll
  for (int r = 0; r < 16; ++r) {
    const int qrow = qw + (r & 3) + 8 * (r >> 2) + 4 * hi;
    const float inv = 1.0f / lred[wid * 32 + (r & 3) + 8 * (r >> 2) + 4 * hi];
    __hip_bfloat16* dst = ob + ((size_t)nidx * SEQ + qrow) * DIMM + hh * 64;
    dst[ln31] = __float2bfloat16(o0[r] * inv);
    dst[32 + ln31] = __float2bfloat16(o1[r] * inv);
  }
}

extern "C" void kernel_launch(void* const* d_in, const int* in_sizes, int n_in,
                              void* d_out, int out_size, void* d_ws, size_t ws_size,
                              hipStream_t stream) {
  const float* x = (const float*)d_in[0];
  const float* ln_w = (const float*)d_in[1];
  const float* ln_b = (const float*)d_in[2];
  const float* w_qkv = (const float*)d_in[3];
  const float* b_qkv = (const float*)d_in[4];
  const float* w_out = (const float*)d_in[5];
  const float* b_out = (const float*)d_in[6];
  float* out = (float*)d_out;

  char* ws = (char*)d_ws;
  size_t off = 0;
  auto alloc = [&](size_t bytes) -> char* {
    char* p = ws + off;
    off += (bytes + 255) & ~(size_t)255;
    return p;
  };
  __hip_bfloat16* h = (__hip_bfloat16*)alloc((size_t)ROWS * DIMM * 2);
  __hip_bfloat16* wqkvT = (__hip_bfloat16*)alloc((size_t)3 * DIMM * DIMM * 2);
  __hip_bfloat16* woutT = (__hip_bfloat16*)alloc((size_t)DIMM * DIMM * 2);
  __hip_bfloat16* qbuf = (__hip_bfloat16*)alloc((size_t)ROWS * DIMM * 2);
  __hip_bfloat16* kbuf = (__hip_bfloat16*)alloc((size_t)ROWS * DIMM * 2);
  __hip_bfloat16* vtbuf = (__hip_bfloat16*)alloc((size_t)ROWS * DIMM * 2);
  __hip_bfloat16* obuf = (__hip_bfloat16*)alloc((size_t)ROWS * DIMM * 2);
  float* ct = (float*)alloc((size_t)SEQ * NFREQ * 4);
  float* st = (float*)alloc((size_t)SEQ * NFREQ * 4);

  rope_tab_kernel<<<dim3((SEQ * NFREQ + 255) / 256), dim3(256), 0, stream>>>(ct, st);
  transpose_cast_kernel<<<dim3(3 * DIMM / 32, DIMM / 32), dim3(32, 8), 0, stream>>>(
      w_qkv, wqkvT, DIMM, 3 * DIMM);
  transpose_cast_kernel<<<dim3(DIMM / 32, DIMM / 32), dim3(32, 8), 0, stream>>>(
      w_out, woutT, DIMM, DIMM);
  ln_kernel<<<dim3(ROWS), dim3(256), 0, stream>>>(x, ln_w, ln_b, h);
  gemm_qkv_kernel<<<dim3(3 * DIMM / 128, ROWS / 256), dim3(256), 0, stream>>>(
      h, wqkvT, b_qkv, ct, st, qbuf, kbuf, vtbuf);
  attn_kernel<<<dim3(NBATCH * NHEADS, SEQ / 128), dim3(256), 0, stream>>>(
      qbuf, kbuf, vtbuf, obuf);
  gemm_out_kernel<<<dim3(DIMM / 128, ROWS / 256), dim3(256), 0, stream>>>(
      obuf, woutT, b_out, x, out);
}

// Round 5
// 276.877 us; speedup vs baseline: 1.0852x; 1.0852x over previous
//
#include <hip/hip_runtime.h>
#include <hip/hip_bf16.h>
#include <cstdint>
#include <cstddef>

#define DIMM 2048
#define NHEADS 32
#define HDIM 64
#define SEQ 2048
#define NBATCH 2
#define ROWS 4096
#define NFREQ 16
#define NKT 32  // K=2048 / BK=64

typedef __bf16 bfv8 __attribute__((ext_vector_type(8)));
typedef float f32x4v __attribute__((ext_vector_type(4)));
typedef float f32x16 __attribute__((ext_vector_type(16)));

__device__ __forceinline__ void gload16(const void* g, void* l) {
  __builtin_amdgcn_global_load_lds((const __attribute__((address_space(1))) void*)g,
                                   (__attribute__((address_space(3))) void*)l, 16, 0, 0);
}

__device__ __forceinline__ f32x4v mfma16(bfv8 a, bfv8 b, f32x4v c) {
  return __builtin_amdgcn_mfma_f32_16x16x32_bf16(a, b, c, 0, 0, 0);
}

__device__ __forceinline__ f32x16 mfma32(bfv8 a, bfv8 b, f32x16 c) {
  return __builtin_amdgcn_mfma_f32_32x32x16_bf16(a, b, c, 0, 0, 0);
}

__device__ __forceinline__ unsigned short f2bfu(float f) {
  __hip_bfloat16 h = __float2bfloat16(f);
  return __builtin_bit_cast(unsigned short, h);
}

__device__ __forceinline__ unsigned pack2bf(float a, float b) {
  return (unsigned)f2bfu(a) | ((unsigned)f2bfu(b) << 16);
}

__device__ __forceinline__ void swap32(unsigned& a, unsigned& b, const int hi) {
  const unsigned ta = (unsigned)__shfl_xor((int)a, 32);
  const unsigned tb = (unsigned)__shfl_xor((int)b, 32);
  const unsigned na = hi ? tb : a;
  const unsigned nb = hi ? b : ta;
  a = na;
  b = nb;
}

__device__ __forceinline__ void xcd_swizzle(int& bx, int& by) {
  const int gx = gridDim.x, nwg = gx * gridDim.y;
  const int orig = blockIdx.y * gx + blockIdx.x;
  const int q = nwg >> 3, r = nwg & 7;
  const int xcd = orig & 7, loc = orig >> 3;
  const int wg = (xcd < r ? xcd * (q + 1) : r * (q + 1) + (xcd - r) * q) + loc;
  bx = wg % gx;
  by = wg / gx;
}

// ---------------- RoPE cos/sin table ----------------
__global__ __launch_bounds__(256) void rope_tab_kernel(float* __restrict__ ct,
                                                       float* __restrict__ st) {
  const int i = blockIdx.x * 256 + threadIdx.x;
  if (i >= SEQ * NFREQ) return;
  const int pos = i >> 4, f = i & 15;
  const float freq = powf(10000.0f, -(float)f / 16.0f);
  const float ang = (float)pos * freq;
  ct[i] = cosf(ang);
  st[i] = sinf(ang);
}

// ---------------- transpose + cast f32[K][N] -> bf16[N][K] ----------------
__global__ __launch_bounds__(256) void transpose_cast_kernel(const float* __restrict__ W,
                                                             __hip_bfloat16* __restrict__ WT,
                                                             int K, int N) {
  __shared__ float tile[32][33];
  const int n0 = blockIdx.x * 32, k0 = blockIdx.y * 32;
  const int tx = threadIdx.x, ty = threadIdx.y;
#pragma unroll
  for (int j = 0; j < 4; ++j)
    tile[ty + j * 8][tx] = W[(size_t)(k0 + ty + j * 8) * N + n0 + tx];
  __syncthreads();
#pragma unroll
  for (int j = 0; j < 4; ++j)
    WT[(size_t)(n0 + ty + j * 8) * K + k0 + tx] = __float2bfloat16(tile[tx][ty + j * 8]);
}

// ---------------- LayerNorm f32 -> bf16 ----------------
__global__ __launch_bounds__(256) void ln_kernel(const float* __restrict__ x,
                                                 const float* __restrict__ lw,
                                                 const float* __restrict__ lb,
                                                 __hip_bfloat16* __restrict__ h) {
  const int row = blockIdx.x;
  const int t = threadIdx.x;
  const float4* xr = (const float4*)(x + (size_t)row * DIMM);
  float4 a = xr[t * 2], b = xr[t * 2 + 1];
  float e[8];
  *(float4*)e = a; *(float4*)(e + 4) = b;
  float s = 0.f, ss = 0.f;
#pragma unroll
  for (int j = 0; j < 8; ++j) { s += e[j]; ss += e[j] * e[j]; }
#pragma unroll
  for (int o = 1; o < 64; o <<= 1) { s += __shfl_xor(s, o); ss += __shfl_xor(ss, o); }
  __shared__ float red[8];
  const int wid = t >> 6;
  if ((t & 63) == 0) { red[wid * 2] = s; red[wid * 2 + 1] = ss; }
  __syncthreads();
  s = red[0] + red[2] + red[4] + red[6];
  ss = red[1] + red[3] + red[5] + red[7];
  const float mu = s * (1.f / DIMM);
  const float var = ss * (1.f / DIMM) - mu * mu;
  const float rs = rsqrtf(var + 1e-5f);
  const float4* w4 = (const float4*)lw;
  const float4* b4 = (const float4*)lb;
  float4 wa = w4[t * 2], wb = w4[t * 2 + 1], ba = b4[t * 2], bb = b4[t * 2 + 1];
  float wv[8], bv[8];
  *(float4*)wv = wa; *(float4*)(wv + 4) = wb;
  *(float4*)bv = ba; *(float4*)(bv + 4) = bb;
  unsigned short hv[8];
#pragma unroll
  for (int j = 0; j < 8; ++j)
    hv[j] = f2bfu((e[j] - mu) * rs * wv[j] + bv[j]);
  *(uint4*)((char*)h + (size_t)row * (DIMM * 2) + t * 16) = *(uint4*)hv;
}

// ======== 256x128xK GEMM, BK=64, 8 waves (4Mx2N), phase-interleaved pipeline ========
// LDS buf (48 KB): A [256 rows][128 B] at +0, B [128 rows][128 B] at +32768. 2 bufs.
// Swizzle: byte ^= ((row&7)<<4) (both sides; == ((ln15&7)<<4) on fragment reads).
// Per K-tile t (buf c=t&1): P1 reads A rows [wr*64..+31] ("even") + all B; P2 reads
// A rows [wr*64+32..+63] ("odd"). Stage of tile t+2: A-even+B in P2(t) (dead after P1),
// A-odd in P1(t+1) (dead after P2(t)). 6 gloads/wave/tile; vmcnt(4) before the
// tile-closing barrier drains tile t+1 while t+2 stays in flight (T4).
__device__ __forceinline__ void stage_chunkA(const char* Ab, int brow, int kt,
                                             char* bufA, int cidx, int odd, int lane) {
  const int q = cidx >> 2, sub = cidx & 3;
  const int r0 = q * 64 + odd * 32 + sub * 8;
  const int row = r0 + (lane >> 3);
  const int src = ((lane & 7) * 16) ^ ((row & 7) << 4);
  gload16(Ab + (size_t)(brow + row) * 4096 + kt * 128 + src, bufA + r0 * 128);
}

__device__ __forceinline__ void stage_chunkB(const char* Bb, int bcol, int kt,
                                             char* bufB, int cidx, int lane) {
  const int r0 = cidx * 8;
  const int row = r0 + (lane >> 3);
  const int src = ((lane & 7) * 16) ^ ((row & 7) << 4);
  gload16(Bb + (size_t)(bcol + row) * 4096 + kt * 128 + src, bufB + r0 * 128);
}

__device__ __forceinline__ void gemm8_core(const char* Ab, const char* Bb,
                                           int brow, int bcol, char* lds,
                                           f32x4v acc[4][4]) {
  const int tid = threadIdx.x, lane = tid & 63, wid = tid >> 6;
  const int g = lane >> 4, ln15 = lane & 15;
  const int wr = wid >> 1, wc = wid & 1;
  const int sw = (ln15 & 7) << 4;
  const size_t arow = (size_t)(wr * 64 + ln15) * 128;
  const size_t brr = (size_t)(wc * 64 + ln15) * 128;

  // prologue: fully stage tiles 0 and 1 (6 gloads/wave each)
#pragma unroll
  for (int t = 0; t < 2; ++t) {
    char* bufA = lds + t * 49152;
    char* bufB = bufA + 32768;
#pragma unroll
    for (int s = 0; s < 2; ++s) stage_chunkA(Ab, brow, t, bufA, s * 8 + wid, 0, lane);
#pragma unroll
    for (int s = 0; s < 2; ++s) stage_chunkA(Ab, brow, t, bufA, s * 8 + wid, 1, lane);
#pragma unroll
    for (int s = 0; s < 2; ++s) stage_chunkB(Bb, bcol, t, bufB, s * 8 + wid, lane);
  }
  asm volatile("s_waitcnt vmcnt(6)" ::: "memory");  // tile 0 landed; tile 1 in flight
  __builtin_amdgcn_s_barrier();

  for (int t = 0; t < NKT; ++t) {
    char* bufA = lds + (t & 1) * 49152;
    char* bufB = bufA + 32768;
    char* nbufA = lds + ((t + 1) & 1) * 49152;
    // ---------- P1: read A-even frags + all B frags; stage (t+1)'s A-odd ----------
    bfv8 a0[2][2], b0[4][2];
#pragma unroll
    for (int mi = 0; mi < 2; ++mi)
#pragma unroll
      for (int ks = 0; ks < 2; ++ks)
        a0[mi][ks] = *(const bfv8*)(bufA + arow + (size_t)mi * 2048 +
                                    ((ks * 64 + g * 16) ^ sw));
#pragma unroll
    for (int nf = 0; nf < 4; ++nf)
#pragma unroll
      for (int ks = 0; ks < 2; ++ks)
        b0[nf][ks] = *(const bfv8*)(bufB + brr + (size_t)nf * 2048 +
                                    ((ks * 64 + g * 16) ^ sw));
    if (t >= 1 && t + 1 < NKT) {
#pragma unroll
      for (int s = 0; s < 2; ++s) stage_chunkA(Ab, brow, t + 1, nbufA, s * 8 + wid, 1, lane);
    }
    asm volatile("" ::: "memory");
    __builtin_amdgcn_s_barrier();
    asm volatile("s_waitcnt lgkmcnt(0)" ::: "memory");
    __builtin_amdgcn_sched_barrier(0);
    __builtin_amdgcn_s_setprio(1);
#pragma unroll
    for (int mi = 0; mi < 2; ++mi)
#pragma unroll
      for (int nf = 0; nf < 4; ++nf) {
        acc[mi][nf] = mfma16(a0[mi][0], b0[nf][0], acc[mi][nf]);
        acc[mi][nf] = mfma16(a0[mi][1], b0[nf][1], acc[mi][nf]);
      }
    __builtin_amdgcn_s_setprio(0);
    asm volatile("" ::: "memory");
    __builtin_amdgcn_s_barrier();
    // ---------- P2: read A-odd frags; stage (t+2)'s A-even + B ----------
    bfv8 a1[2][2];
#pragma unroll
    for (int mi = 0; mi < 2; ++mi)
#pragma unroll
      for (int ks = 0; ks < 2; ++ks)
        a1[mi][ks] = *(const bfv8*)(bufA + arow + 4096 + (size_t)mi * 2048 +
                                    ((ks * 64 + g * 16) ^ sw));
    if (t + 2 < NKT) {
#pragma unroll
      for (int s = 0; s < 2; ++s) stage_chunkA(Ab, brow, t + 2, bufA, s * 8 + wid, 0, lane);
#pragma unroll
      for (int s = 0; s < 2; ++s) stage_chunkB(Bb, bcol, t + 2, bufB, s * 8 + wid, lane);
    }
    asm volatile("" ::: "memory");
    __builtin_amdgcn_s_barrier();
    asm volatile("s_waitcnt lgkmcnt(0)" ::: "memory");
    __builtin_amdgcn_sched_barrier(0);
    __builtin_amdgcn_s_setprio(1);
#pragma unroll
    for (int mi = 0; mi < 2; ++mi)
#pragma unroll
      for (int nf = 0; nf < 4; ++nf) {
        acc[2 + mi][nf] = mfma16(a1[mi][0], b0[nf][0], acc[2 + mi][nf]);
        acc[2 + mi][nf] = mfma16(a1[mi][1], b0[nf][1], acc[2 + mi][nf]);
      }
    __builtin_amdgcn_s_setprio(0);
    // counted drain of tile t+1 BEFORE the closing barrier (all waves publish)
    if (t + 1 < NKT) {
      if (t + 1 == NKT - 1) {
        asm volatile("s_waitcnt vmcnt(0)" ::: "memory");
      } else {
        asm volatile("s_waitcnt vmcnt(4)" ::: "memory");
      }
    }
    asm volatile("" ::: "memory");
    __builtin_amdgcn_s_barrier();
  }
}

// ---------------- QKV GEMM + bias + RoPE; q,k -> [n*h][s][64]; v -> VT ----------------
__global__ __launch_bounds__(512, 2) void gemm_qkv_kernel(
    const __hip_bfloat16* __restrict__ A, const __hip_bfloat16* __restrict__ BT,
    const float* __restrict__ bqkv, const float* __restrict__ ct, const float* __restrict__ st,
    __hip_bfloat16* __restrict__ qb, __hip_bfloat16* __restrict__ kb,
    __hip_bfloat16* __restrict__ vb) {
  __shared__ char lds[98304];
  const f32x4v fz = {0.f, 0.f, 0.f, 0.f};
  f32x4v acc[4][4];
#pragma unroll
  for (int mf = 0; mf < 4; ++mf)
#pragma unroll
    for (int nf = 0; nf < 4; ++nf) acc[mf][nf] = fz;
  int bx, by;
  xcd_swizzle(bx, by);
  const int brow = by * 256, bcol = bx * 128;
  gemm8_core((const char*)A, (const char*)BT, brow, bcol, lds, acc);

  const int tid = threadIdx.x, lane = tid & 63, wid = tid >> 6;
  const int g = lane >> 4, ln15 = lane & 15;
  const int wr = wid >> 1, wc = wid & 1;
  const int cb = bcol + wc * 64;
  const int which = cb >> 11;
  const int head = (cb & 2047) >> 6;
  float bias[4];
#pragma unroll
  for (int nf = 0; nf < 4; ++nf) bias[nf] = bqkv[cb + nf * 16 + ln15];

  if (which == 2) {
    // V: transpose wave's 64pos x 64d subtile via wave-private LDS, store VT coalesced
    char* tp = lds + wid * 8192;
    const int nidx = brow >> 11;
    const size_t vhead = ((size_t)nidx * NHEADS + head) * (HDIM * SEQ);
    const int posb = (brow & 2047) + wr * 64;
#pragma unroll
    for (int mf = 0; mf < 4; ++mf)
#pragma unroll
      for (int r = 0; r < 4; ++r) {
        const int posl = mf * 16 + g * 4 + r;
#pragma unroll
        for (int nf = 0; nf < 4; ++nf) {
          const int d = nf * 16 + ln15;
          *(unsigned short*)(tp + d * 128 + ((posl * 2) ^ ((d & 7) << 4))) =
              f2bfu(acc[mf][nf][r] + bias[nf]);
        }
      }
    asm volatile("s_waitcnt lgkmcnt(0)" ::: "memory");
    __builtin_amdgcn_sched_barrier(0);
#pragma unroll
    for (int i = 0; i < 8; ++i) {
      const int dl = i * 8 + (lane >> 3);
      const int cs = (lane & 7) ^ (dl & 7);
      const uint4 val = *(const uint4*)(tp + dl * 128 + cs * 16);
      *(uint4*)((char*)vb + (vhead + (size_t)dl * SEQ + posb + (lane & 7) * 8) * 2) = val;
    }
  } else {
    __hip_bfloat16* dst = (which == 0) ? qb : kb;
#pragma unroll
    for (int mf = 0; mf < 4; ++mf)
#pragma unroll
      for (int r = 0; r < 4; ++r) {
        const int row = brow + wr * 64 + mf * 16 + g * 4 + r;
        const int nidx = row >> 11, pos = row & 2047;
        float v0 = acc[mf][0][r] + bias[0];
        float v1 = acc[mf][1][r] + bias[1];
        float v2 = acc[mf][2][r] + bias[2];
        float v3 = acc[mf][3][r] + bias[3];
        const float c0 = ct[pos * 16 + ln15], s0 = st[pos * 16 + ln15];
        const float x1 = v0, x2 = v1;
        v0 = x1 * c0 - x2 * s0;
        v1 = x2 * c0 + x1 * s0;
        __hip_bfloat16* p = dst + (((size_t)(nidx * NHEADS + head)) * SEQ + pos) * HDIM;
        p[ln15] = __float2bfloat16(v0);
        p[16 + ln15] = __float2bfloat16(v1);
        p[32 + ln15] = __float2bfloat16(v2);
        p[48 + ln15] = __float2bfloat16(v3);
      }
  }
}

// ---------------- out-proj GEMM + bias + residual -> f32 out ----------------
__global__ __launch_bounds__(512, 2) void gemm_out_kernel(
    const __hip_bfloat16* __restrict__ A, const __hip_bfloat16* __restrict__ BT,
    const float* __restrict__ bout, const float* __restrict__ skip,
    float* __restrict__ out) {
  __shared__ char lds[98304];
  const f32x4v fz = {0.f, 0.f, 0.f, 0.f};
  f32x4v acc[4][4];
#pragma unroll
  for (int mf = 0; mf < 4; ++mf)
#pragma unroll
    for (int nf = 0; nf < 4; ++nf) acc[mf][nf] = fz;
  int bx, by;
  xcd_swizzle(bx, by);
  const int brow = by * 256, bcol = bx * 128;
  gemm8_core((const char*)A, (const char*)BT, brow, bcol, lds, acc);

  const int tid = threadIdx.x, lane = tid & 63, wid = tid >> 6;
  const int g = lane >> 4, ln15 = lane & 15;
  const int wr = wid >> 1, wc = wid & 1;
#pragma unroll
  for (int mf = 0; mf < 4; ++mf)
#pragma unroll
    for (int r = 0; r < 4; ++r) {
      const int row = brow + wr * 64 + mf * 16 + g * 4 + r;
      const float* xr = skip + (size_t)row * DIMM;
      float* orow = out + (size_t)row * DIMM;
#pragma unroll
      for (int nf = 0; nf < 4; ++nf) {
        const int c = bcol + wc * 64 + nf * 16 + ln15;
        orow[c] = acc[mf][nf][r] + bout[c] + xr[c];
      }
    }
}

// ---------------- causal flash attention, swapped-QK^T 32x32 structure ----------------
__global__ __launch_bounds__(256) void attn_kernel(
    const __hip_bfloat16* __restrict__ qb, const __hip_bfloat16* __restrict__ kb,
    const __hip_bfloat16* __restrict__ vtb, __hip_bfloat16* __restrict__ ob) {
  __shared__ char sm[33280];  // K dbuf 2x8K | VT dbuf 2x8K | lred 512B
  float* lred = (float*)(sm + 32768);
  const int tid = threadIdx.x, lane = tid & 63, wid = tid >> 6;
  const int ln31 = lane & 31, hi = lane >> 5;
  const int head = blockIdx.x;
  const int qbi = (int)gridDim.y - 1 - (int)blockIdx.y;  // heavy blocks dispatch first
  const size_t hb = (size_t)head * (SEQ * HDIM);
  const int q0 = qbi * 128;
  const int qw = q0 + wid * 32;
  const int qg = qw + ln31;
  const int nt = qbi * 2 + 2;
  const char* Kg = (const char*)(kb + hb);
  const char* Vg = (const char*)(vtb + hb);

  bfv8 qf[4];
  {
    const char* Qp = (const char*)(qb + hb) + (size_t)(qw + ln31) * 128 + hi * 16;
#pragma unroll
    for (int j = 0; j < 4; ++j) qf[j] = *(const bfv8*)(Qp + j * 32);
  }

  f32x16 o0, o1;
#pragma unroll
  for (int i = 0; i < 16; ++i) { o0[i] = 0.f; o1[i] = 0.f; }
  float m_run = -1e30f, l_run = 0.f;
  const float scale = 0.125f;
  const int swz = (ln31 & 7) << 4;

#pragma unroll
  for (int i = 0; i < 2; ++i) {
    const int f = (tid + i * 256) * 16;
    const int row = f >> 7;
    const int src = (f & 127) ^ ((row & 7) << 4);
    gload16(Kg + (size_t)row * 128 + src, sm + f);
    gload16(Vg + (size_t)row * 4096 + src, sm + 16384 + f);
  }
  asm volatile("s_waitcnt vmcnt(0)" ::: "memory");
  __syncthreads();

  for (int t = 0; t < nt; ++t) {
    const int kvb = t * 64;
    if (t + 1 < nt) {
      const int nb = (t + 1) & 1;
      const int kvb2 = kvb + 64;
#pragma unroll
      for (int i = 0; i < 2; ++i) {
        const int f = (tid + i * 256) * 16;
        const int row = f >> 7;
        const int src = (f & 127) ^ ((row & 7) << 4);
        gload16(Kg + (size_t)(kvb2 + row) * 128 + src, sm + nb * 8192 + f);
        gload16(Vg + (size_t)row * 4096 + (size_t)kvb2 * 2 + src, sm + 16384 + nb * 8192 + f);
      }
    }
    if (kvb <= qw + 31) {
      const char* ldsK = sm + (t & 1) * 8192;
      const char* ldsV = sm + 16384 + (t & 1) * 8192;
      f32x16 s0, s1;
#pragma unroll
      for (int i = 0; i < 16; ++i) { s0[i] = 0.f; s1[i] = 0.f; }
      __builtin_amdgcn_s_setprio(1);
#pragma unroll
      for (int j = 0; j < 4; ++j) {
        const int byt = j * 32 + hi * 16;
        const bfv8 k0 = *(const bfv8*)(ldsK + ln31 * 128 + (byt ^ swz));
        const bfv8 k1 = *(const bfv8*)(ldsK + (32 + ln31) * 128 + (byt ^ swz));
        s0 = mfma32(k0, qf[j], s0);
        s1 = mfma32(k1, qf[j], s1);
      }
      __builtin_amdgcn_s_setprio(0);
      float p[32];
#pragma unroll
      for (int r = 0; r < 16; ++r) { p[r] = s0[r] * scale; p[16 + r] = s1[r] * scale; }
      if (kvb + 63 > qw) {  // diagonal tile for this wave (compare vs MIN q-row)
#pragma unroll
        for (int r = 0; r < 16; ++r) {
          const int kvo = (r & 3) + 8 * (r >> 2) + 4 * hi;
          if (kvb + kvo > qg) p[r] = -1e30f;
          if (kvb + 32 + kvo > qg) p[16 + r] = -1e30f;
        }
      }
      float mx = p[0];
#pragma unroll
      for (int r = 1; r < 32; ++r) mx = fmaxf(mx, p[r]);
      mx = fmaxf(mx, __shfl_xor(mx, 32));
      if (!__all(mx <= m_run + 8.0f)) {  // defer-max (T13, THR=8)
        const float mn = fmaxf(m_run, mx);
        const float al = __expf(m_run - mn);
        m_run = mn;
        l_run *= al;
        lred[wid * 32 + ln31] = al;
        asm volatile("s_waitcnt lgkmcnt(0)" ::: "memory");
        __builtin_amdgcn_sched_barrier(0);
#pragma unroll
        for (int r = 0; r < 16; ++r) {
          const float a = lred[wid * 32 + (r & 3) + 8 * (r >> 2) + 4 * hi];
          o0[r] *= a;
          o1[r] *= a;
        }
      }
      float ps = 0.f;
#pragma unroll
      for (int r = 0; r < 32; ++r) { p[r] = __expf(p[r] - m_run); ps += p[r]; }
      ps += __shfl_xor(ps, 32);
      l_run += ps;
      unsigned c[16];
#pragma unroll
      for (int i = 0; i < 16; ++i) c[i] = pack2bf(p[2 * i], p[2 * i + 1]);
      bfv8 paf[4];
#pragma unroll
      for (int fI = 0; fI < 4; ++fI) {
        unsigned a0 = c[fI * 4 + 0], b0 = c[fI * 4 + 2];
        unsigned a1 = c[fI * 4 + 1], b1 = c[fI * 4 + 3];
        swap32(a0, b0, hi);
        swap32(a1, b1, hi);
        union { unsigned u[4]; bfv8 v; } w;
        w.u[0] = a0; w.u[1] = a1; w.u[2] = b0; w.u[3] = b1;
        paf[fI] = w.v;
      }
      __builtin_amdgcn_s_setprio(1);
#pragma unroll
      for (int ss = 0; ss < 4; ++ss) {
        const int byt = ss * 32 + hi * 16;
        const bfv8 v0 = *(const bfv8*)(ldsV + ln31 * 128 + (byt ^ swz));
        const bfv8 v1 = *(const bfv8*)(ldsV + (32 + ln31) * 128 + (byt ^ swz));
        o0 = mfma32(paf[ss], v0, o0);
        o1 = mfma32(paf[ss], v1, o1);
      }
      __builtin_amdgcn_s_setprio(0);
    }
    asm volatile("s_waitcnt vmcnt(0)" ::: "memory");
    __syncthreads();
  }

  lred[wid * 32 + ln31] = l_run;
  asm volatile("s_waitcnt lgkmcnt(0)" ::: "memory");
  __builtin_amdgcn_sched_barrier(0);
  const int nidx = head >> 5, hh = head & 31;
#pragma unroll
  for (int r = 0; r < 16; ++r) {
    const int qrow = qw + (r & 3) + 8 * (r >> 2) + 4 * hi;
    const float inv = 1.0f / lred[wid * 32 + (r & 3) + 8 * (r >> 2) + 4 * hi];
    __hip_bfloat16* dst = ob + ((size_t)nidx * SEQ + qrow) * DIMM + hh * 64;
    dst[ln31] = __float2bfloat16(o0[r] * inv);
    dst[32 + ln31] = __float2bfloat16(o1[r] * inv);
  }
}

extern "C" void kernel_launch(void* const* d_in, const int* in_sizes, int n_in,
                              void* d_out, int out_size, void* d_ws, size_t ws_size,
                              hipStream_t stream) {
  const float* x = (const float*)d_in[0];
  const float* ln_w = (const float*)d_in[1];
  const float* ln_b = (const float*)d_in[2];
  const float* w_qkv = (const float*)d_in[3];
  const float* b_qkv = (const float*)d_in[4];
  const float* w_out = (const float*)d_in[5];
  const float* b_out = (const float*)d_in[6];
  float* out = (float*)d_out;

  char* ws = (char*)d_ws;
  size_t off = 0;
  auto alloc = [&](size_t bytes) -> char* {
    char* p = ws + off;
    off += (bytes + 255) & ~(size_t)255;
    return p;
  };
  __hip_bfloat16* h = (__hip_bfloat16*)alloc((size_t)ROWS * DIMM * 2);
  __hip_bfloat16* wqkvT = (__hip_bfloat16*)alloc((size_t)3 * DIMM * DIMM * 2);
  __hip_bfloat16* woutT = (__hip_bfloat16*)alloc((size_t)DIMM * DIMM * 2);
  __hip_bfloat16* qbuf = (__hip_bfloat16*)alloc((size_t)ROWS * DIMM * 2);
  __hip_bfloat16* kbuf = (__hip_bfloat16*)alloc((size_t)ROWS * DIMM * 2);
  __hip_bfloat16* vtbuf = (__hip_bfloat16*)alloc((size_t)ROWS * DIMM * 2);
  __hip_bfloat16* obuf = (__hip_bfloat16*)alloc((size_t)ROWS * DIMM * 2);
  float* ct = (float*)alloc((size_t)SEQ * NFREQ * 4);
  float* st = (float*)alloc((size_t)SEQ * NFREQ * 4);

  rope_tab_kernel<<<dim3((SEQ * NFREQ + 255) / 256), dim3(256), 0, stream>>>(ct, st);
  transpose_cast_kernel<<<dim3(3 * DIMM / 32, DIMM / 32), dim3(32, 8), 0, stream>>>(
      w_qkv, wqkvT, DIMM, 3 * DIMM);
  transpose_cast_kernel<<<dim3(DIMM / 32, DIMM / 32), dim3(32, 8), 0, stream>>>(
      w_out, woutT, DIMM, DIMM);
  ln_kernel<<<dim3(ROWS), dim3(256), 0, stream>>>(x, ln_w, ln_b, h);
  gemm_qkv_kernel<<<dim3(3 * DIMM / 128, ROWS / 256), dim3(512), 0, stream>>>(
      h, wqkvT, b_qkv, ct, st, qbuf, kbuf, vtbuf);
  attn_kernel<<<dim3(NBATCH * NHEADS, SEQ / 128), dim3(256), 0, stream>>>(
      qbuf, kbuf, vtbuf, obuf);
  gemm_out_kernel<<<dim3(DIMM / 128, ROWS / 256), dim3(512), 0, stream>>>(
      obuf, woutT, b_out, x, out);
}

// Round 6
// 271.755 us; speedup vs baseline: 1.1056x; 1.0188x over previous
//
#include <hip/hip_runtime.h>
#include <hip/hip_bf16.h>
#include <cstdint>
#include <cstddef>

#define DIMM 2048
#define NHEADS 32
#define HDIM 64
#define SEQ 2048
#define NBATCH 2
#define ROWS 4096
#define NFREQ 16
#define NKT3 32  // K=2048 / BK=64

typedef __bf16 bfv8 __attribute__((ext_vector_type(8)));
typedef float f32x4v __attribute__((ext_vector_type(4)));
typedef float f32x16 __attribute__((ext_vector_type(16)));

__device__ __forceinline__ void gload16(const void* g, void* l) {
  __builtin_amdgcn_global_load_lds((const __attribute__((address_space(1))) void*)g,
                                   (__attribute__((address_space(3))) void*)l, 16, 0, 0);
}

__device__ __forceinline__ f32x4v mfma16(bfv8 a, bfv8 b, f32x4v c) {
  return __builtin_amdgcn_mfma_f32_16x16x32_bf16(a, b, c, 0, 0, 0);
}

__device__ __forceinline__ f32x16 mfma32(bfv8 a, bfv8 b, f32x16 c) {
  return __builtin_amdgcn_mfma_f32_32x32x16_bf16(a, b, c, 0, 0, 0);
}

__device__ __forceinline__ unsigned short f2bfu(float f) {
  __hip_bfloat16 h = __float2bfloat16(f);
  return __builtin_bit_cast(unsigned short, h);
}

__device__ __forceinline__ unsigned pack2bf(float a, float b) {
  return (unsigned)f2bfu(a) | ((unsigned)f2bfu(b) << 16);
}

__device__ __forceinline__ void swap32(unsigned& a, unsigned& b, const int hi) {
  const unsigned ta = (unsigned)__shfl_xor((int)a, 32);
  const unsigned tb = (unsigned)__shfl_xor((int)b, 32);
  const unsigned na = hi ? tb : a;
  const unsigned nb = hi ? b : ta;
  a = na;
  b = nb;
}

__device__ __forceinline__ void xcd_swizzle(int& bx, int& by) {
  const int gx = gridDim.x, nwg = gx * gridDim.y;
  const int orig = blockIdx.y * gx + blockIdx.x;
  const int q = nwg >> 3, r = nwg & 7;
  const int xcd = orig & 7, loc = orig >> 3;
  const int wg = (xcd < r ? xcd * (q + 1) : r * (q + 1) + (xcd - r) * q) + loc;
  bx = wg % gx;
  by = wg / gx;
}

// ---------------- RoPE cos/sin table ----------------
__global__ __launch_bounds__(256) void rope_tab_kernel(float* __restrict__ ct,
                                                       float* __restrict__ st) {
  const int i = blockIdx.x * 256 + threadIdx.x;
  if (i >= SEQ * NFREQ) return;
  const int pos = i >> 4, f = i & 15;
  const float freq = powf(10000.0f, -(float)f / 16.0f);
  const float ang = (float)pos * freq;
  ct[i] = cosf(ang);
  st[i] = sinf(ang);
}

// ---------------- transpose + cast f32[K][N] -> bf16[N][K] ----------------
__global__ __launch_bounds__(256) void transpose_cast_kernel(const float* __restrict__ W,
                                                             __hip_bfloat16* __restrict__ WT,
                                                             int K, int N) {
  __shared__ float tile[32][33];
  const int n0 = blockIdx.x * 32, k0 = blockIdx.y * 32;
  const int tx = threadIdx.x, ty = threadIdx.y;
#pragma unroll
  for (int j = 0; j < 4; ++j)
    tile[ty + j * 8][tx] = W[(size_t)(k0 + ty + j * 8) * N + n0 + tx];
  __syncthreads();
#pragma unroll
  for (int j = 0; j < 4; ++j)
    WT[(size_t)(n0 + ty + j * 8) * K + k0 + tx] = __float2bfloat16(tile[tx][ty + j * 8]);
}

// ---------------- LayerNorm f32 -> bf16 ----------------
__global__ __launch_bounds__(256) void ln_kernel(const float* __restrict__ x,
                                                 const float* __restrict__ lw,
                                                 const float* __restrict__ lb,
                                                 __hip_bfloat16* __restrict__ h) {
  const int row = blockIdx.x;
  const int t = threadIdx.x;
  const float4* xr = (const float4*)(x + (size_t)row * DIMM);
  float4 a = xr[t * 2], b = xr[t * 2 + 1];
  float e[8];
  *(float4*)e = a; *(float4*)(e + 4) = b;
  float s = 0.f, ss = 0.f;
#pragma unroll
  for (int j = 0; j < 8; ++j) { s += e[j]; ss += e[j] * e[j]; }
#pragma unroll
  for (int o = 1; o < 64; o <<= 1) { s += __shfl_xor(s, o); ss += __shfl_xor(ss, o); }
  __shared__ float red[8];
  const int wid = t >> 6;
  if ((t & 63) == 0) { red[wid * 2] = s; red[wid * 2 + 1] = ss; }
  __syncthreads();
  s = red[0] + red[2] + red[4] + red[6];
  ss = red[1] + red[3] + red[5] + red[7];
  const float mu = s * (1.f / DIMM);
  const float var = ss * (1.f / DIMM) - mu * mu;
  const float rs = rsqrtf(var + 1e-5f);
  const float4* w4 = (const float4*)lw;
  const float4* b4 = (const float4*)lb;
  float4 wa = w4[t * 2], wb = w4[t * 2 + 1], ba = b4[t * 2], bb = b4[t * 2 + 1];
  float wv[8], bv[8];
  *(float4*)wv = wa; *(float4*)(wv + 4) = wb;
  *(float4*)bv = ba; *(float4*)(bv + 4) = bb;
  unsigned short hv[8];
#pragma unroll
  for (int j = 0; j < 8; ++j)
    hv[j] = f2bfu((e[j] - mu) * rs * wv[j] + bv[j]);
  *(uint4*)((char*)h + (size_t)row * (DIMM * 2) + t * 16) = *(uint4*)hv;
}

// ======== 256x128xK GEMM, BK=64, 8 waves = 2M x 2N x 2K, ring-3 LDS ========
// Waves (wr,wc,wk): partial 128x64 C over k-slice wk (bytes wk*64 of each 128B row).
// Buf (48KB): A 256x128B at +0, B 128x128B at +32768; ring of 3 (144KB).
// Swizzle: slot ^= (row&7) on both stage-source and read. One s_barrier +
// boundary vmcnt(6) per K-tile; tile t stages t+2 into buf holding t-1 (dead).
__device__ __forceinline__ void stageA64(const char* Ab, int brow, int kt,
                                         char* bufA, int c, int lane) {
  const int row = c * 8 + (lane >> 3);
  const int src = ((lane & 7) * 16) ^ ((row & 7) << 4);
  gload16(Ab + (size_t)(brow + row) * 4096 + kt * 128 + src, bufA + c * 1024);
}
__device__ __forceinline__ void stageB64(const char* Bb, int bcol, int kt,
                                         char* bufB, int c, int lane) {
  const int row = c * 8 + (lane >> 3);
  const int src = ((lane & 7) * 16) ^ ((row & 7) << 4);
  gload16(Bb + (size_t)(bcol + row) * 4096 + kt * 128 + src, bufB + c * 1024);
}

__device__ __forceinline__ void gemm_core3(const char* Ab, const char* Bb,
                                           int brow, int bcol, char* lds,
                                           f32x4v acc[8][4]) {
  const int tid = threadIdx.x, lane = tid & 63, wid = tid >> 6;
  const int g = lane >> 4, ln15 = lane & 15;
  const int wr = wid >> 2, wc = (wid >> 1) & 1, wk = wid & 1;
  const int kb = wk * 64;

  // prologue: stage tiles 0 and 1 (6 gloads/wave each)
#pragma unroll
  for (int t = 0; t < 2; ++t) {
    char* bufA = lds + t * 49152;
    char* bufB = bufA + 32768;
    stageA64(Ab, brow, t, bufA, wid, lane);
    stageA64(Ab, brow, t, bufA, wid + 8, lane);
    stageA64(Ab, brow, t, bufA, wid + 16, lane);
    stageA64(Ab, brow, t, bufA, wid + 24, lane);
    stageB64(Bb, bcol, t, bufB, wid, lane);
    stageB64(Bb, bcol, t, bufB, wid + 8, lane);
  }
  asm volatile("s_waitcnt vmcnt(6)" ::: "memory");  // tile0 landed; tile1 in flight
  __builtin_amdgcn_s_barrier();

  for (int t = 0; t < NKT3; ++t) {
    char* bufA = lds + (t % 3) * 49152;
    char* bufB = bufA + 32768;
    char* nbufA = lds + ((t + 2) % 3) * 49152;
    char* nbufB = nbufA + 32768;
    const bool st = (t + 2 < NKT3);
    // ---- half 1: read A mi0-3 + all B; stage 3 chunks of t+2; 16 MFMA ----
    bfv8 af[4], bfr[4];
#pragma unroll
    for (int mi = 0; mi < 4; ++mi) {
      const int ra = wr * 128 + mi * 16 + ln15;
      af[mi] = *(const bfv8*)(bufA + (size_t)ra * 128 + ((kb + g * 16) ^ ((ra & 7) << 4)));
    }
#pragma unroll
    for (int nf = 0; nf < 4; ++nf) {
      const int rb = wc * 64 + nf * 16 + ln15;
      bfr[nf] = *(const bfv8*)(bufB + (size_t)rb * 128 + ((kb + g * 16) ^ ((rb & 7) << 4)));
    }
    if (st) {
      stageA64(Ab, brow, t + 2, nbufA, wid, lane);
      stageA64(Ab, brow, t + 2, nbufA, wid + 8, lane);
      stageB64(Bb, bcol, t + 2, nbufB, wid, lane);
    }
    asm volatile("s_waitcnt lgkmcnt(0)" ::: "memory");
    __builtin_amdgcn_sched_barrier(0);
    __builtin_amdgcn_s_setprio(1);
#pragma unroll
    for (int mi = 0; mi < 4; ++mi)
#pragma unroll
      for (int nf = 0; nf < 4; ++nf)
        acc[mi][nf] = mfma16(af[mi], bfr[nf], acc[mi][nf]);
    __builtin_amdgcn_s_setprio(0);
    // ---- half 2: read A mi4-7; stage remaining 3 chunks; 16 MFMA ----
    bfv8 ao[4];
#pragma unroll
    for (int mi = 0; mi < 4; ++mi) {
      const int ra = wr * 128 + (4 + mi) * 16 + ln15;
      ao[mi] = *(const bfv8*)(bufA + (size_t)ra * 128 + ((kb + g * 16) ^ ((ra & 7) << 4)));
    }
    if (st) {
      stageA64(Ab, brow, t + 2, nbufA, wid + 16, lane);
      stageA64(Ab, brow, t + 2, nbufA, wid + 24, lane);
      stageB64(Bb, bcol, t + 2, nbufB, wid + 8, lane);
    }
    asm volatile("s_waitcnt lgkmcnt(0)" ::: "memory");
    __builtin_amdgcn_sched_barrier(0);
    __builtin_amdgcn_s_setprio(1);
#pragma unroll
    for (int mi = 0; mi < 4; ++mi)
#pragma unroll
      for (int nf = 0; nf < 4; ++nf)
        acc[4 + mi][nf] = mfma16(ao[mi], bfr[nf], acc[4 + mi][nf]);
    __builtin_amdgcn_s_setprio(0);
    if (st) {
      asm volatile("s_waitcnt vmcnt(6)" ::: "memory");  // t+1 landed; t+2 in flight
    } else if (t == NKT3 - 2) {
      asm volatile("s_waitcnt vmcnt(0)" ::: "memory");  // drain last tile
    }
    __builtin_amdgcn_s_barrier();
  }
}

// Cross-wave K-reduction: wave keeps rows wk*64..+64 of its 128; partner supplies
// the other k-half. Regions lds + wid*16KB (128KB, reuses ring bufs post-loop).
__device__ __forceinline__ void kreduce(char* lds, f32x4v acc[8][4], f32x4v ak[4][4],
                                        int wid, int lane, int wk) {
  char* reg = lds + (size_t)wid * 16384;
#pragma unroll
  for (int q = 0; q < 4; ++q)
#pragma unroll
    for (int nf = 0; nf < 4; ++nf)
      *(f32x4v*)(reg + (q * 4 + nf) * 1024 + lane * 16) = acc[wk ? q : 4 + q][nf];
  __syncthreads();
  const char* preg = lds + (size_t)(wid ^ 1) * 16384;
#pragma unroll
  for (int q = 0; q < 4; ++q)
#pragma unroll
    for (int nf = 0; nf < 4; ++nf)
      ak[q][nf] = acc[wk ? 4 + q : q][nf] +
                  *(const f32x4v*)(preg + (q * 4 + nf) * 1024 + lane * 16);
  __syncthreads();
}

// ---------------- QKV GEMM + bias + RoPE; q,k -> [n*h][s][64]; v -> VT ----------------
__global__ __launch_bounds__(512, 2) void gemm_qkv_kernel(
    const __hip_bfloat16* __restrict__ A, const __hip_bfloat16* __restrict__ BT,
    const float* __restrict__ bqkv, const float* __restrict__ ct, const float* __restrict__ st,
    __hip_bfloat16* __restrict__ qb, __hip_bfloat16* __restrict__ kb,
    __hip_bfloat16* __restrict__ vb) {
  __shared__ char lds[147456];
  const f32x4v fz = {0.f, 0.f, 0.f, 0.f};
  f32x4v acc[8][4];
#pragma unroll
  for (int mf = 0; mf < 8; ++mf)
#pragma unroll
    for (int nf = 0; nf < 4; ++nf) acc[mf][nf] = fz;
  int bx, by;
  xcd_swizzle(bx, by);
  const int brow = by * 256, bcol = bx * 128;
  gemm_core3((const char*)A, (const char*)BT, brow, bcol, lds, acc);

  const int tid = threadIdx.x, lane = tid & 63, wid = tid >> 6;
  const int g = lane >> 4, ln15 = lane & 15;
  const int wr = wid >> 2, wc = (wid >> 1) & 1, wk = wid & 1;
  f32x4v ak[4][4];
  kreduce(lds, acc, ak, wid, lane, wk);

  const int cb = bcol + wc * 64;
  const int which = cb >> 11;
  const int head = (cb & 2047) >> 6;
  const int rowbase = brow + wr * 128 + wk * 64;
  float bias[4];
#pragma unroll
  for (int nf = 0; nf < 4; ++nf) bias[nf] = bqkv[cb + nf * 16 + ln15];

  if (which == 2) {
    // V: transpose wave's 64pos x 64d subtile via wave-private LDS, store VT coalesced
    char* tp = lds + wid * 8192;
    const int nidx = brow >> 11;
    const size_t vhead = ((size_t)nidx * NHEADS + head) * (HDIM * SEQ);
    const int posb = (rowbase & 2047);
#pragma unroll
    for (int q = 0; q < 4; ++q)
#pragma unroll
      for (int r = 0; r < 4; ++r) {
        const int posl = q * 16 + g * 4 + r;
#pragma unroll
        for (int nf = 0; nf < 4; ++nf) {
          const int d = nf * 16 + ln15;
          *(unsigned short*)(tp + d * 128 + ((posl * 2) ^ ((d & 7) << 4))) =
              f2bfu(ak[q][nf][r] + bias[nf]);
        }
      }
    asm volatile("s_waitcnt lgkmcnt(0)" ::: "memory");
    __builtin_amdgcn_sched_barrier(0);
#pragma unroll
    for (int i = 0; i < 8; ++i) {
      const int dl = i * 8 + (lane >> 3);
      const int cs = (lane & 7) ^ (dl & 7);
      const uint4 val = *(const uint4*)(tp + dl * 128 + cs * 16);
      *(uint4*)((char*)vb + (vhead + (size_t)dl * SEQ + posb + (lane & 7) * 8) * 2) = val;
    }
  } else {
    __hip_bfloat16* dst = (which == 0) ? qb : kb;
#pragma unroll
    for (int q = 0; q < 4; ++q)
#pragma unroll
      for (int r = 0; r < 4; ++r) {
        const int row = rowbase + q * 16 + g * 4 + r;
        const int nidx = row >> 11, pos = row & 2047;
        float v0 = ak[q][0][r] + bias[0];
        float v1 = ak[q][1][r] + bias[1];
        float v2 = ak[q][2][r] + bias[2];
        float v3 = ak[q][3][r] + bias[3];
        const float c0 = ct[pos * 16 + ln15], s0 = st[pos * 16 + ln15];
        const float x1 = v0, x2 = v1;
        v0 = x1 * c0 - x2 * s0;
        v1 = x2 * c0 + x1 * s0;
        __hip_bfloat16* p = dst + (((size_t)(nidx * NHEADS + head)) * SEQ + pos) * HDIM;
        p[ln15] = __float2bfloat16(v0);
        p[16 + ln15] = __float2bfloat16(v1);
        p[32 + ln15] = __float2bfloat16(v2);
        p[48 + ln15] = __float2bfloat16(v3);
      }
  }
}

// ---------------- out-proj GEMM + bias + residual -> f32 out ----------------
__global__ __launch_bounds__(512, 2) void gemm_out_kernel(
    const __hip_bfloat16* __restrict__ A, const __hip_bfloat16* __restrict__ BT,
    const float* __restrict__ bout, const float* __restrict__ skip,
    float* __restrict__ out) {
  __shared__ char lds[147456];
  const f32x4v fz = {0.f, 0.f, 0.f, 0.f};
  f32x4v acc[8][4];
#pragma unroll
  for (int mf = 0; mf < 8; ++mf)
#pragma unroll
    for (int nf = 0; nf < 4; ++nf) acc[mf][nf] = fz;
  int bx, by;
  xcd_swizzle(bx, by);
  const int brow = by * 256, bcol = bx * 128;
  gemm_core3((const char*)A, (const char*)BT, brow, bcol, lds, acc);

  const int tid = threadIdx.x, lane = tid & 63, wid = tid >> 6;
  const int g = lane >> 4, ln15 = lane & 15;
  const int wr = wid >> 2, wc = (wid >> 1) & 1, wk = wid & 1;
  f32x4v ak[4][4];
  kreduce(lds, acc, ak, wid, lane, wk);

  const int rowbase = brow + wr * 128 + wk * 64;
#pragma unroll
  for (int q = 0; q < 4; ++q)
#pragma unroll
    for (int r = 0; r < 4; ++r) {
      const int row = rowbase + q * 16 + g * 4 + r;
      const float* xr = skip + (size_t)row * DIMM;
      float* orow = out + (size_t)row * DIMM;
#pragma unroll
      for (int nf = 0; nf < 4; ++nf) {
        const int c = bcol + wc * 64 + nf * 16 + ln15;
        orow[c] = ak[q][nf][r] + bout[c] + xr[c];
      }
    }
}

// ---------------- causal flash attention, swapped-QK^T 32x32 structure ----------------
__global__ __launch_bounds__(256) void attn_kernel(
    const __hip_bfloat16* __restrict__ qb, const __hip_bfloat16* __restrict__ kb,
    const __hip_bfloat16* __restrict__ vtb, __hip_bfloat16* __restrict__ ob) {
  __shared__ char sm[33280];  // K dbuf 2x8K | VT dbuf 2x8K | lred 512B
  float* lred = (float*)(sm + 32768);
  const int tid = threadIdx.x, lane = tid & 63, wid = tid >> 6;
  const int ln31 = lane & 31, hi = lane >> 5;
  const int head = blockIdx.x;
  const int qbi = (int)gridDim.y - 1 - (int)blockIdx.y;  // heavy blocks dispatch first
  const size_t hb = (size_t)head * (SEQ * HDIM);
  const int q0 = qbi * 128;
  const int qw = q0 + wid * 32;
  const int qg = qw + ln31;
  const int nt = qbi * 2 + 2;
  const char* Kg = (const char*)(kb + hb);
  const char* Vg = (const char*)(vtb + hb);

  bfv8 qf[4];
  {
    const char* Qp = (const char*)(qb + hb) + (size_t)(qw + ln31) * 128 + hi * 16;
#pragma unroll
    for (int j = 0; j < 4; ++j) qf[j] = *(const bfv8*)(Qp + j * 32);
  }

  f32x16 o0, o1;
#pragma unroll
  for (int i = 0; i < 16; ++i) { o0[i] = 0.f; o1[i] = 0.f; }
  float m_run = -1e30f, l_run = 0.f;
  const float scale = 0.125f;
  const int swz = (ln31 & 7) << 4;

#pragma unroll
  for (int i = 0; i < 2; ++i) {
    const int f = (tid + i * 256) * 16;
    const int row = f >> 7;
    const int src = (f & 127) ^ ((row & 7) << 4);
    gload16(Kg + (size_t)row * 128 + src, sm + f);
    gload16(Vg + (size_t)row * 4096 + src, sm + 16384 + f);
  }
  asm volatile("s_waitcnt vmcnt(0)" ::: "memory");
  __syncthreads();

  for (int t = 0; t < nt; ++t) {
    const int kvb = t * 64;
    if (t + 1 < nt) {
      const int nb = (t + 1) & 1;
      const int kvb2 = kvb + 64;
#pragma unroll
      for (int i = 0; i < 2; ++i) {
        const int f = (tid + i * 256) * 16;
        const int row = f >> 7;
        const int src = (f & 127) ^ ((row & 7) << 4);
        gload16(Kg + (size_t)(kvb2 + row) * 128 + src, sm + nb * 8192 + f);
        gload16(Vg + (size_t)row * 4096 + (size_t)kvb2 * 2 + src, sm + 16384 + nb * 8192 + f);
      }
    }
    if (kvb <= qw + 31) {
      const char* ldsK = sm + (t & 1) * 8192;
      const char* ldsV = sm + 16384 + (t & 1) * 8192;
      f32x16 s0, s1;
#pragma unroll
      for (int i = 0; i < 16; ++i) { s0[i] = 0.f; s1[i] = 0.f; }
      __builtin_amdgcn_s_setprio(1);
#pragma unroll
      for (int j = 0; j < 4; ++j) {
        const int byt = j * 32 + hi * 16;
        const bfv8 k0 = *(const bfv8*)(ldsK + ln31 * 128 + (byt ^ swz));
        const bfv8 k1 = *(const bfv8*)(ldsK + (32 + ln31) * 128 + (byt ^ swz));
        s0 = mfma32(k0, qf[j], s0);
        s1 = mfma32(k1, qf[j], s1);
      }
      __builtin_amdgcn_s_setprio(0);
      float p[32];
#pragma unroll
      for (int r = 0; r < 16; ++r) { p[r] = s0[r] * scale; p[16 + r] = s1[r] * scale; }
      if (kvb + 63 > qw) {  // diagonal tile for this wave (compare vs MIN q-row)
#pragma unroll
        for (int r = 0; r < 16; ++r) {
          const int kvo = (r & 3) + 8 * (r >> 2) + 4 * hi;
          if (kvb + kvo > qg) p[r] = -1e30f;
          if (kvb + 32 + kvo > qg) p[16 + r] = -1e30f;
        }
      }
      float mx = p[0];
#pragma unroll
      for (int r = 1; r < 32; ++r) mx = fmaxf(mx, p[r]);
      mx = fmaxf(mx, __shfl_xor(mx, 32));
      if (!__all(mx <= m_run + 8.0f)) {  // defer-max (T13, THR=8)
        const float mn = fmaxf(m_run, mx);
        const float al = __expf(m_run - mn);
        m_run = mn;
        l_run *= al;
        lred[wid * 32 + ln31] = al;
        asm volatile("s_waitcnt lgkmcnt(0)" ::: "memory");
        __builtin_amdgcn_sched_barrier(0);
#pragma unroll
        for (int r = 0; r < 16; ++r) {
          const float a = lred[wid * 32 + (r & 3) + 8 * (r >> 2) + 4 * hi];
          o0[r] *= a;
          o1[r] *= a;
        }
      }
      float ps = 0.f;
#pragma unroll
      for (int r = 0; r < 32; ++r) { p[r] = __expf(p[r] - m_run); ps += p[r]; }
      ps += __shfl_xor(ps, 32);
      l_run += ps;
      unsigned c[16];
#pragma unroll
      for (int i = 0; i < 16; ++i) c[i] = pack2bf(p[2 * i], p[2 * i + 1]);
      bfv8 paf[4];
#pragma unroll
      for (int fI = 0; fI < 4; ++fI) {
        unsigned a0 = c[fI * 4 + 0], b0 = c[fI * 4 + 2];
        unsigned a1 = c[fI * 4 + 1], b1 = c[fI * 4 + 3];
        swap32(a0, b0, hi);
        swap32(a1, b1, hi);
        union { unsigned u[4]; bfv8 v; } w;
        w.u[0] = a0; w.u[1] = a1; w.u[2] = b0; w.u[3] = b1;
        paf[fI] = w.v;
      }
      __builtin_amdgcn_s_setprio(1);
#pragma unroll
      for (int ss = 0; ss < 4; ++ss) {
        const int byt = ss * 32 + hi * 16;
        const bfv8 v0 = *(const bfv8*)(ldsV + ln31 * 128 + (byt ^ swz));
        const bfv8 v1 = *(const bfv8*)(ldsV + (32 + ln31) * 128 + (byt ^ swz));
        o0 = mfma32(paf[ss], v0, o0);
        o1 = mfma32(paf[ss], v1, o1);
      }
      __builtin_amdgcn_s_setprio(0);
    }
    asm volatile("s_waitcnt vmcnt(0)" ::: "memory");
    __syncthreads();
  }

  lred[wid * 32 + ln31] = l_run;
  asm volatile("s_waitcnt lgkmcnt(0)" ::: "memory");
  __builtin_amdgcn_sched_barrier(0);
  const int nidx = head >> 5, hh = head & 31;
#pragma unroll
  for (int r = 0; r < 16; ++r) {
    const int qrow = qw + (r & 3) + 8 * (r >> 2) + 4 * hi;
    const float inv = 1.0f / lred[wid * 32 + (r & 3) + 8 * (r >> 2) + 4 * hi];
    __hip_bfloat16* dst = ob + ((size_t)nidx * SEQ + qrow) * DIMM + hh * 64;
    dst[ln31] = __float2bfloat16(o0[r] * inv);
    dst[32 + ln31] = __float2bfloat16(o1[r] * inv);
  }
}

extern "C" void kernel_launch(void* const* d_in, const int* in_sizes, int n_in,
                              void* d_out, int out_size, void* d_ws, size_t ws_size,
                              hipStream_t stream) {
  const float* x = (const float*)d_in[0];
  const float* ln_w = (const float*)d_in[1];
  const float* ln_b = (const float*)d_in[2];
  const float* w_qkv = (const float*)d_in[3];
  const float* b_qkv = (const float*)d_in[4];
  const float* w_out = (const float*)d_in[5];
  const float* b_out = (const float*)d_in[6];
  float* out = (float*)d_out;

  char* ws = (char*)d_ws;
  size_t off = 0;
  auto alloc = [&](size_t bytes) -> char* {
    char* p = ws + off;
    off += (bytes + 255) & ~(size_t)255;
    return p;
  };
  __hip_bfloat16* h = (__hip_bfloat16*)alloc((size_t)ROWS * DIMM * 2);
  __hip_bfloat16* wqkvT = (__hip_bfloat16*)alloc((size_t)3 * DIMM * DIMM * 2);
  __hip_bfloat16* woutT = (__hip_bfloat16*)alloc((size_t)DIMM * DIMM * 2);
  __hip_bfloat16* qbuf = (__hip_bfloat16*)alloc((size_t)ROWS * DIMM * 2);
  __hip_bfloat16* kbuf = (__hip_bfloat16*)alloc((size_t)ROWS * DIMM * 2);
  __hip_bfloat16* vtbuf = (__hip_bfloat16*)alloc((size_t)ROWS * DIMM * 2);
  __hip_bfloat16* obuf = (__hip_bfloat16*)alloc((size_t)ROWS * DIMM * 2);
  float* ct = (float*)alloc((size_t)SEQ * NFREQ * 4);
  float* st = (float*)alloc((size_t)SEQ * NFREQ * 4);

  rope_tab_kernel<<<dim3((SEQ * NFREQ + 255) / 256), dim3(256), 0, stream>>>(ct, st);
  transpose_cast_kernel<<<dim3(3 * DIMM / 32, DIMM / 32), dim3(32, 8), 0, stream>>>(
      w_qkv, wqkvT, DIMM, 3 * DIMM);
  transpose_cast_kernel<<<dim3(DIMM / 32, DIMM / 32), dim3(32, 8), 0, stream>>>(
      w_out, woutT, DIMM, DIMM);
  ln_kernel<<<dim3(ROWS), dim3(256), 0, stream>>>(x, ln_w, ln_b, h);
  gemm_qkv_kernel<<<dim3(3 * DIMM / 128, ROWS / 256), dim3(512), 0, stream>>>(
      h, wqkvT, b_qkv, ct, st, qbuf, kbuf, vtbuf);
  attn_kernel<<<dim3(NBATCH * NHEADS, SEQ / 128), dim3(256), 0, stream>>>(
      qbuf, kbuf, vtbuf, obuf);
  gemm_out_kernel<<<dim3(DIMM / 128, ROWS / 256), dim3(512), 0, stream>>>(
      obuf, woutT, b_out, x, out);
}